// Round 7
// baseline (12108.854 us; speedup 1.0000x reference)
//
#include <hip/hip_runtime.h>
#include <hip/hip_bf16.h>

// ContTimeLSTM: L=512, B=32, DIN=512, H=1024.
// Persistent kernel: 64 WGs x 512 threads (8 waves, 2/SIMD, 256-VGPR cap).
// WG g owns h-columns [16g, 16g+16) => 96 projection rows.
// Waves 0-5: gate rows (16 each); wave 6: d-row; wave 7: spare (stage/epilogue).
// Weights live in REGISTERS (48 x bf16x8 = 192 VGPR per lane).
// x A-fragments load directly from global (L2/L3-resident, overlaps barrier).
// h staged once/WG via coalesced sc1 dwordx4 loads into swizzled LDS.
// Packed ushort epoch flags; all cross-WG data via sc1 accesses.

#define L_STEPS 512
#define BATCH   32
#define DIN     512
#define HDIM    1024
#define KDIM    1536
#define NWG     64
#define CPW     16
#define NTHREADS 512

// LDS layout (bytes)
#define LDS_HB    0                      // [32][1024] bf16 swizzled (64 KB)
#define LDS_PROJ  65536                  // 96*33 floats = 12672 B
#define LDS_DLS   78208                  // 32 floats
#define LDS_HSTG  78336                  // 32*16 bf16 = 1024 B
#define LDS_BYTES 79360

#define WS_FLAGS_BYTES 1024              // 64 ushorts used

typedef __attribute__((ext_vector_type(8))) __bf16 bf16x8;
typedef __attribute__((ext_vector_type(4))) float  f32x4;
typedef __attribute__((ext_vector_type(4))) unsigned int u32x4;

__device__ __forceinline__ float fsigmoid(float u) { return 1.0f / (1.0f + __expf(-u)); }

__device__ __forceinline__ bf16x8 pack8(float4 fa, float4 fb) {
    bf16x8 v;
    v[0] = (__bf16)fa.x; v[1] = (__bf16)fa.y; v[2] = (__bf16)fa.z; v[3] = (__bf16)fa.w;
    v[4] = (__bf16)fb.x; v[5] = (__bf16)fb.y; v[6] = (__bf16)fb.z; v[7] = (__bf16)fb.w;
    return v;
}

extern "C" __global__ void __launch_bounds__(NTHREADS, 1)
ctlstm_kernel(const float* __restrict__ x,
              const float* __restrict__ tdel,
              const float* __restrict__ o_state,
              const float* __restrict__ cs_state,
              const float* __restrict__ ce_state,
              const float* __restrict__ d_state,
              const float* __restrict__ weight,
              const float* __restrict__ bias,
              const float* __restrict__ d_weight,
              const float* __restrict__ d_bias,
              const float* __restrict__ d_beta_p,
              float* __restrict__ out0,
              float* __restrict__ out1,
              unsigned short* __restrict__ flags,
              __bf16* __restrict__ h0,
              __bf16* __restrict__ h1)
{
    extern __shared__ char smem[];
    char*   hbp  = smem + LDS_HB;
    float*  proj = (float*)(smem + LDS_PROJ);
    float*  dls  = (float*)(smem + LDS_DLS);
    __bf16* hstg = (__bf16*)(smem + LDS_HSTG);

    const int tid = threadIdx.x;
    const int wg  = blockIdx.x;
    const int c0  = wg * CPW;

    const int wv = tid >> 6;       // 0..7
    const int l  = tid & 63;
    const int lr = l & 15;
    const int lk = l >> 4;

    // per-thread persistent state: (b, j), j in [0,16)
    const int b = tid >> 4, j = tid & 15;
    float s_o, s_cs, s_ce, dt_cur;
    {
        int gi = b * HDIM + c0 + j;
        s_o = o_state[gi]; s_cs = cs_state[gi]; s_ce = ce_state[gi];
        dt_cur = tdel[b];
    }
    if (tid < BATCH) dls[tid] = d_state[tid];

    // ---- startup: weights into registers (192 VGPR) ----
    bf16x8 Bx[16], Bh[32];
    float bias_r = 0.f;
    {
        const float* wsrc = nullptr;
        if (wv < 6) {
            wsrc = weight + (size_t)(wv * HDIM + c0 + lr) * KDIM;
            bias_r = bias[wv * HDIM + c0 + lr];
        } else if (wv == 6 && lr == 0) {
            wsrc = d_weight;
        }
        #pragma unroll
        for (int kc = 0; kc < 48; ++kc) {
            bf16x8 v = {};
            if (wsrc) {
                float4 fa = *(const float4*)(wsrc + kc * 32 + lk * 8);
                float4 fb = *(const float4*)(wsrc + kc * 32 + lk * 8 + 4);
                v = pack8(fa, fb);
            }
            if (kc < 16) Bx[kc] = v; else Bh[kc - 16] = v;
        }
    }
    const float dbias_s = d_bias[0];
    const float beta    = d_beta_p[0];

    __syncthreads();

    for (int t = 0; t < L_STEPS; ++t) {
        __bf16* hcur = (t & 1) ? h1 : h0;

        // ---- phase 1: c, h; stage h slice in LDS ----
        float dv = dls[b];
        float c  = s_cs + (s_ce - s_cs) * __expf(-dv * dt_cur);
        float h_reg = s_o * (1.f - 2.f / (__expf(2.f * c) + 1.f));  // o*tanh(c)
        float c_reg = c;
        hstg[b * CPW + j] = (__bf16)h_reg;
        __syncthreads();   // S1

        // ---- wave 0: publish 1 KB h slice (16-B sc1 stores), ack, flag ----
        if (tid < 64) {
            int bb = tid >> 1, half = tid & 1;
            u32x4 v = *(const u32x4*)((const char*)hstg + tid * 16);
            void* dst = (char*)hcur + (size_t)bb * 2048 + c0 * 2 + half * 16;
            asm volatile("global_store_dwordx4 %0, %1, off sc1" :: "v"(dst), "v"(v) : "memory");
            asm volatile("s_waitcnt vmcnt(0)" ::: "memory");
            if (tid == 0)
                __hip_atomic_store(flags + wg, (unsigned short)(t + 1),
                                   __ATOMIC_RELAXED, __HIP_MEMORY_SCOPE_AGENT);
            asm volatile("" ::: "memory");
        }

        // ---- off-path: out0 store + tdel prefetch ----
        __builtin_nontemporal_store(h_reg, out0 + ((size_t)b * L_STEPS + t) * HDIM + c0 + j);
        int tn = (t + 1 < L_STEPS) ? t + 1 : t;
        float dt_nxt = tdel[tn * BATCH + b];

        // ---- x-part MFMA: A-frags direct from global (overlaps barrier) ----
        f32x4 acc0 = {0.f, 0.f, 0.f, 0.f};
        f32x4 acc1 = {0.f, 0.f, 0.f, 0.f};
        if (wv < 7) {
            const float* xr0 = x + ((size_t)t * BATCH + lr) * DIN;
            const float* xr1 = xr0 + 16 * DIN;
            #pragma unroll
            for (int kc = 0; kc < 16; ++kc) {
                const int k = kc * 32 + lk * 8;
                float4 fa0 = *(const float4*)(xr0 + k);
                float4 fb0 = *(const float4*)(xr0 + k + 4);
                float4 fa1 = *(const float4*)(xr1 + k);
                float4 fb1 = *(const float4*)(xr1 + k + 4);
                bf16x8 a0 = pack8(fa0, fb0);
                bf16x8 a1 = pack8(fa1, fb1);
                acc0 = __builtin_amdgcn_mfma_f32_16x16x32_bf16(a0, Bx[kc], acc0, 0, 0, 0);
                acc1 = __builtin_amdgcn_mfma_f32_16x16x32_bf16(a1, Bx[kc], acc1, 0, 0, 0);
            }
        }

        // ---- wave 0 polls packed flags (1 line), then barrier ----
        if (tid < 64) {
            const unsigned tgt = (unsigned)(t + 1);
            const unsigned* fl = (const unsigned*)flags + (l & 31);
            for (;;) {
                unsigned v = __hip_atomic_load(fl, __ATOMIC_RELAXED, __HIP_MEMORY_SCOPE_AGENT);
                if (__all((int)((v & 0xFFFFu) >= tgt && (v >> 16) >= tgt))) break;
            }
        }
        __syncthreads();   // S2: all h published

        // ---- stage h: 8 x 16-B coalesced sc1 loads/thread -> swizzled LDS ----
        {
            const char* hsrc = (const char*)hcur + tid * 128;
            u32x4 q[8];
            #pragma unroll
            for (int i = 0; i < 8; ++i) {
                const void* p = hsrc + i * 16;
                asm volatile("global_load_dwordx4 %0, %1, off sc1"
                             : "=v"(q[i]) : "v"(p) : "memory");
            }
            asm volatile("s_waitcnt vmcnt(0)" ::: "memory");
            #pragma unroll
            for (int i = 0; i < 8; ++i) {
                int g = tid * 128 + i * 16;
                int bt = g >> 11, colb = g & 2047;
                unsigned ba = (unsigned)(bt * 2048) + ((unsigned)colb ^ (((unsigned)bt & 7) << 4));
                *(u32x4*)(hbp + ba) = q[i];
            }
        }
        __syncthreads();   // S_stage: h tile ready

        // ---- h-part MFMA from LDS h tile ----
        if (wv < 7) {
            const unsigned swz = ((unsigned)(lr & 7)) << 4;
            #pragma unroll
            for (int kc = 0; kc < 32; ++kc) {
                unsigned cb = (unsigned)(kc * 64 + lk * 16);
                bf16x8 a0 = *(const bf16x8*)(hbp + lr * 2048 + (cb ^ swz));
                bf16x8 a1 = *(const bf16x8*)(hbp + (16 + lr) * 2048 + (cb ^ swz));
                acc0 = __builtin_amdgcn_mfma_f32_16x16x32_bf16(a0, Bh[kc], acc0, 0, 0, 0);
                acc1 = __builtin_amdgcn_mfma_f32_16x16x32_bf16(a1, Bh[kc], acc1, 0, 0, 0);
            }
            if (wv < 6) {
                const int n = wv * 16 + lr;
                #pragma unroll
                for (int r = 0; r < 4; ++r) {
                    proj[n * 33 + lk * 4 + r]      = fsigmoid(acc0[r] + bias_r);
                    proj[n * 33 + 16 + lk * 4 + r] = fsigmoid(acc1[r] + bias_r);
                }
            } else if (lr == 0) {
                #pragma unroll
                for (int r = 0; r < 4; ++r) {
                    int b0 = lk * 4 + r, b1 = 16 + lk * 4 + r;
                    float bu0 = beta * (acc0[r] + dbias_s);
                    float bu1 = beta * (acc1[r] + dbias_s);
                    float sp0 = fmaxf(bu0, 0.f) + __logf(1.f + __expf(-fabsf(bu0)));
                    float sp1 = fmaxf(bu1, 0.f) + __logf(1.f + __expf(-fabsf(bu1)));
                    float dn0 = sp0 / beta, dn1 = sp1 / beta;
                    dls[b0] = dn0; dls[b1] = dn1;
                    if (wg == 0) {
                        __builtin_nontemporal_store(dn0, out1 + ((size_t)b0 * L_STEPS + t) * 3073 + 3072);
                        __builtin_nontemporal_store(dn1, out1 + ((size_t)b1 * L_STEPS + t) * 3073 + 3072);
                    }
                }
            }
        }
        __syncthreads();   // S3

        // ---- epilogue: gate algebra, state update, outputs (64-B chunks) ----
        {
            float gi  = proj[(0 * 16 + j) * 33 + b];
            float gf  = proj[(1 * 16 + j) * 33 + b];
            float gie = proj[(2 * 16 + j) * 33 + b];
            float gfe = proj[(3 * 16 + j) * 33 + b];
            float gz  = proj[(4 * 16 + j) * 33 + b];
            float go  = proj[(5 * 16 + j) * 33 + b];
            float z   = 2.f * gz - 1.f;
            float csn = gf * c_reg + gi * z;
            float cen = gfe * s_ce + gie * z;
            size_t ob = ((size_t)b * L_STEPS + t) * 3073;
            __builtin_nontemporal_store(go,  out1 + ob + c0 + j);
            __builtin_nontemporal_store(csn, out1 + ob + HDIM + c0 + j);
            __builtin_nontemporal_store(cen, out1 + ob + 2 * HDIM + c0 + j);
            s_o = go; s_cs = csn; s_ce = cen;
        }
        dt_cur = dt_nxt;
    }
}

extern "C" void kernel_launch(void* const* d_in, const int* in_sizes, int n_in,
                              void* d_out, int out_size, void* d_ws, size_t ws_size,
                              hipStream_t stream) {
    const float* x        = (const float*)d_in[0];
    const float* tdel     = (const float*)d_in[1];
    const float* o_state  = (const float*)d_in[2];
    const float* cs_state = (const float*)d_in[3];
    const float* ce_state = (const float*)d_in[4];
    const float* d_state  = (const float*)d_in[5];
    const float* weight   = (const float*)d_in[6];
    const float* bias     = (const float*)d_in[7];
    const float* d_weight = (const float*)d_in[8];
    const float* d_bias   = (const float*)d_in[9];
    const float* d_beta   = (const float*)d_in[10];

    float* out0 = (float*)d_out;
    float* out1 = out0 + (size_t)BATCH * L_STEPS * HDIM;

    unsigned short* flags = (unsigned short*)d_ws;
    __bf16* h0 = (__bf16*)((char*)d_ws + WS_FLAGS_BYTES);
    __bf16* h1 = (__bf16*)((char*)d_ws + WS_FLAGS_BYTES + (size_t)BATCH * HDIM * 2);

    (void)hipMemsetAsync(d_ws, 0, WS_FLAGS_BYTES, stream);  // re-arm flags every launch
    (void)hipFuncSetAttribute((const void*)ctlstm_kernel,
                              hipFuncAttributeMaxDynamicSharedMemorySize, LDS_BYTES);
    ctlstm_kernel<<<NWG, NTHREADS, LDS_BYTES, stream>>>(
        x, tdel, o_state, cs_state, ce_state, d_state,
        weight, bias, d_weight, d_bias, d_beta,
        out0, out1, flags, h0, h1);
}

// Round 8
// 4507.962 us; speedup vs baseline: 2.6861x; 2.6861x over previous
//
#include <hip/hip_runtime.h>
#include <hip/hip_bf16.h>

// ContTimeLSTM: L=512, B=32, DIN=512, H=1024.
// Persistent kernel: 128 WGs x 256 threads (4 waves, 1/SIMD, VGPR cap 512).
// WG g owns h-columns [8g, 8g+8) => 48 projection rows.
// Waves 0-2: gate rows (16 each); wave 3: d-row (B nonzero in lane lr==0 only).
// Weights in REGISTERS (48 x bf16x8 per lane). LDS: double-buffered x tile
// (bf16, 2D-XOR swizzled), h tile staged once/step via coalesced sc1
// dwordx4 loads (2D-XOR swizzled writes). Packed ushort epoch flags.

#define L_STEPS 512
#define BATCH   32
#define DIN     512
#define HDIM    1024
#define KDIM    1536
#define NWG     128
#define CPW     8
#define NTHREADS 256

// LDS layout (bytes)
#define LDS_XB0   0        // [32][512] bf16 swizzled  (32 KB)
#define LDS_XB1   32768
#define LDS_HB    65536    // [32][1024] bf16 swizzled (64 KB)
#define LDS_PROJ  131072   // 48*33 floats (6336 B)
#define LDS_DLS   137408   // 32 floats
#define LDS_HSTG  137536   // 256 bf16 (512 B)
#define LDS_BYTES 138048

#define WS_FLAGS_BYTES 1024              // 128 ushorts used

typedef __attribute__((ext_vector_type(8))) __bf16 bf16x8;
typedef __attribute__((ext_vector_type(4))) float  f32x4;
typedef __attribute__((ext_vector_type(4))) unsigned int u32x4;

__device__ __forceinline__ float fsigmoid(float u) { return 1.0f / (1.0f + __expf(-u)); }

__device__ __forceinline__ bf16x8 pack8(float4 fa, float4 fb) {
    bf16x8 v;
    v[0] = (__bf16)fa.x; v[1] = (__bf16)fa.y; v[2] = (__bf16)fa.z; v[3] = (__bf16)fa.w;
    v[4] = (__bf16)fb.x; v[5] = (__bf16)fb.y; v[6] = (__bf16)fb.z; v[7] = (__bf16)fb.w;
    return v;
}

// x tile: [32][512] bf16, row stride 1024 B. 2D key spreads both the
// stage-writes (row const, col varies per lane) and MFMA reads (row varies).
__device__ __forceinline__ void xstage_write(char* xt, int tid, const float4* xr) {
    #pragma unroll
    for (int m = 0; m < 8; ++m) {
        unsigned row  = (unsigned)tid >> 3;
        unsigned colb = ((unsigned)tid & 7) * 128 + (unsigned)m * 16;
        unsigned key  = ((row ^ (colb >> 7)) & 7) << 4;
        *(bf16x8*)(xt + row * 1024 + (colb ^ key)) = pack8(xr[2 * m], xr[2 * m + 1]);
    }
}

extern "C" __global__ void __launch_bounds__(NTHREADS, 1)
ctlstm_kernel(const float* __restrict__ x,
              const float* __restrict__ tdel,
              const float* __restrict__ o_state,
              const float* __restrict__ cs_state,
              const float* __restrict__ ce_state,
              const float* __restrict__ d_state,
              const float* __restrict__ weight,
              const float* __restrict__ bias,
              const float* __restrict__ d_weight,
              const float* __restrict__ d_bias,
              const float* __restrict__ d_beta_p,
              float* __restrict__ out0,
              float* __restrict__ out1,
              unsigned short* __restrict__ flags,
              __bf16* __restrict__ h0,
              __bf16* __restrict__ h1)
{
    extern __shared__ char smem[];
    char*   hbp  = smem + LDS_HB;
    float*  proj = (float*)(smem + LDS_PROJ);
    float*  dls  = (float*)(smem + LDS_DLS);
    __bf16* hstg = (__bf16*)(smem + LDS_HSTG);

    const int tid = threadIdx.x;
    const int wg  = blockIdx.x;
    const int c0  = wg * CPW;

    const int wv = tid >> 6;       // 0..3: waves 0-2 gates, wave 3 = d
    const int l  = tid & 63;
    const int lr = l & 15;
    const int lk = l >> 4;

    // per-thread persistent state: (b, j), j in [0,8)
    const int b = tid >> 3, j = tid & 7;
    float s_o, s_cs, s_ce, dt_cur;
    {
        int gi = b * HDIM + c0 + j;
        s_o = o_state[gi]; s_cs = cs_state[gi]; s_ce = ce_state[gi];
        dt_cur = tdel[b];
    }
    if (tid < BATCH) dls[tid] = d_state[tid];

    // ---- startup: weights into registers (48 x bf16x8 per lane) ----
    bf16x8 Bx[16], Bh[32];
    float bias_r = 0.f;
    {
        const float* wsrc = nullptr;
        if (wv < 3) {
            int n = wv * 16 + lr, g = n >> 3, jj = n & 7;
            wsrc = weight + (size_t)(g * HDIM + c0 + jj) * KDIM;
            bias_r = bias[g * HDIM + c0 + jj];
        } else if (lr == 0) {
            wsrc = d_weight;
        }
        #pragma unroll
        for (int kc = 0; kc < 48; ++kc) {
            bf16x8 v = {};
            if (wsrc) {
                float4 fa = *(const float4*)(wsrc + kc * 32 + lk * 8);
                float4 fb = *(const float4*)(wsrc + kc * 32 + lk * 8 + 4);
                v = pack8(fa, fb);
            }
            if (kc < 16) Bx[kc] = v; else Bh[kc - 16] = v;
        }
    }
    const float dbias_s = d_bias[0];
    const float beta    = d_beta_p[0];

    // ---- startup: stage x panel 0 ----
    {
        float4 x0[16];
        const char* xp = (const char*)x + tid * 256;
        #pragma unroll
        for (int i = 0; i < 16; ++i) x0[i] = *(const float4*)(xp + i * 16);
        xstage_write(smem + LDS_XB0, tid, x0);
    }
    __syncthreads();

    for (int t = 0; t < L_STEPS; ++t) {
        __bf16* hcur = (t & 1) ? h1 : h0;
        char* xcur = smem + ((t & 1) ? LDS_XB1 : LDS_XB0);
        char* xnxt = smem + ((t & 1) ? LDS_XB0 : LDS_XB1);

        // ---- phase 1: c, h; stage h slice in LDS ----
        float dv = dls[b];
        float c  = s_cs + (s_ce - s_cs) * __expf(-dv * dt_cur);
        float h_reg = s_o * (1.f - 2.f / (__expf(2.f * c) + 1.f));  // o*tanh(c)
        float c_reg = c;
        hstg[b * CPW + j] = (__bf16)h_reg;
        __syncthreads();   // S1

        // ---- wave 0: publish 512-B h slice (16-B sc1 stores), ack, flag ----
        if (tid < 64) {
            if (tid < 32) {
                u32x4 v = *(const u32x4*)((const char*)hstg + tid * 16);
                void* dst = (char*)hcur + (size_t)tid * 2048 + (unsigned)wg * 16;
                asm volatile("global_store_dwordx4 %0, %1, off sc1" :: "v"(dst), "v"(v) : "memory");
            }
            asm volatile("s_waitcnt vmcnt(0)" ::: "memory");
            if (tid == 0)
                __hip_atomic_store(flags + wg, (unsigned short)(t + 1),
                                   __ATOMIC_RELAXED, __HIP_MEMORY_SCOPE_AGENT);
            asm volatile("" ::: "memory");
        }

        // ---- off-path: out0 store + tdel prefetch + next x panel loads ----
        __builtin_nontemporal_store(h_reg, out0 + ((size_t)b * L_STEPS + t) * HDIM + c0 + j);
        int tn = (t + 1 < L_STEPS) ? t + 1 : t;
        float dt_nxt = tdel[tn * BATCH + b];
        float4 xr[16];
        {
            const char* xp = (const char*)(x + (size_t)tn * BATCH * DIN) + tid * 256;
            #pragma unroll
            for (int i = 0; i < 16; ++i) xr[i] = *(const float4*)(xp + i * 16);
        }

        // ---- x-part MFMA (overlaps barrier window) ----
        f32x4 acc0 = {0.f, 0.f, 0.f, 0.f};
        f32x4 acc1 = {0.f, 0.f, 0.f, 0.f};
        {
            #pragma unroll
            for (int kc = 0; kc < 16; ++kc) {
                unsigned colb = (unsigned)(kc * 64 + lk * 16);
                unsigned key  = (((unsigned)lr ^ (unsigned)(kc >> 1)) & 7) << 4;
                bf16x8 a0 = *(const bf16x8*)(xcur + lr * 1024 + (colb ^ key));
                bf16x8 a1 = *(const bf16x8*)(xcur + (16 + lr) * 1024 + (colb ^ key));
                acc0 = __builtin_amdgcn_mfma_f32_16x16x32_bf16(a0, Bx[kc], acc0, 0, 0, 0);
                acc1 = __builtin_amdgcn_mfma_f32_16x16x32_bf16(a1, Bx[kc], acc1, 0, 0, 0);
            }
        }

        // ---- wave 0 polls packed flags (4 lines) ----
        if (tid < 64) {
            const unsigned tgt = (unsigned)(t + 1);
            const unsigned* fl = (const unsigned*)flags + l;   // 64 dwords = 128 flags
            for (;;) {
                unsigned v = __hip_atomic_load(fl, __ATOMIC_RELAXED, __HIP_MEMORY_SCOPE_AGENT);
                if (__all((int)((v & 0xFFFFu) >= tgt && (v >> 16) >= tgt))) break;
            }
        }
        __syncthreads();   // S2: all h published

        // ---- stage h: 16 x 16-B coalesced sc1 loads/thread -> swizzled LDS ----
        {
            const char* hsrc = (const char*)hcur + tid * 256;
            u32x4 q[16];
            #pragma unroll
            for (int i = 0; i < 16; ++i) {
                const void* p = hsrc + i * 16;
                asm volatile("global_load_dwordx4 %0, %1, off sc1"
                             : "=v"(q[i]) : "v"(p) : "memory");
            }
            asm volatile("s_waitcnt vmcnt(0)" ::: "memory");
            #pragma unroll
            for (int i = 0; i < 16; ++i) {
                unsigned g    = (unsigned)tid * 256 + (unsigned)i * 16;
                unsigned row  = g >> 11;
                unsigned colb = g & 2047;
                unsigned key  = ((row ^ (colb >> 7)) & 7) << 4;
                *(u32x4*)(hbp + row * 2048 + (colb ^ key)) = q[i];
            }
        }
        __syncthreads();   // S_stage: h tile ready

        // ---- convert + write next x panel (off critical path) ----
        xstage_write(xnxt, tid, xr);

        // ---- h-part MFMA ----
        {
            #pragma unroll
            for (int kc = 0; kc < 32; ++kc) {
                unsigned colb = (unsigned)(kc * 64 + lk * 16);
                unsigned key  = (((unsigned)lr ^ (unsigned)(kc >> 1)) & 7) << 4;
                bf16x8 a0 = *(const bf16x8*)(hbp + lr * 2048 + (colb ^ key));
                bf16x8 a1 = *(const bf16x8*)(hbp + (16 + lr) * 2048 + (colb ^ key));
                acc0 = __builtin_amdgcn_mfma_f32_16x16x32_bf16(a0, Bh[kc], acc0, 0, 0, 0);
                acc1 = __builtin_amdgcn_mfma_f32_16x16x32_bf16(a1, Bh[kc], acc1, 0, 0, 0);
            }
        }

        if (wv < 3) {
            const int n = wv * 16 + lr;
            #pragma unroll
            for (int r = 0; r < 4; ++r) {
                proj[n * 33 + lk * 4 + r]      = fsigmoid(acc0[r] + bias_r);
                proj[n * 33 + 16 + lk * 4 + r] = fsigmoid(acc1[r] + bias_r);
            }
        } else if (lr == 0) {
            #pragma unroll
            for (int r = 0; r < 4; ++r) {
                int b0 = lk * 4 + r, b1 = 16 + lk * 4 + r;
                float bu0 = beta * (acc0[r] + dbias_s);
                float bu1 = beta * (acc1[r] + dbias_s);
                float sp0 = fmaxf(bu0, 0.f) + __logf(1.f + __expf(-fabsf(bu0)));
                float sp1 = fmaxf(bu1, 0.f) + __logf(1.f + __expf(-fabsf(bu1)));
                float dn0 = sp0 / beta, dn1 = sp1 / beta;
                dls[b0] = dn0; dls[b1] = dn1;
                if (wg == 0) {
                    __builtin_nontemporal_store(dn0, out1 + ((size_t)b0 * L_STEPS + t) * 3073 + 3072);
                    __builtin_nontemporal_store(dn1, out1 + ((size_t)b1 * L_STEPS + t) * 3073 + 3072);
                }
            }
        }
        __syncthreads();   // S3: proj + dls ready

        // ---- epilogue: gate algebra, state update, outputs ----
        {
            float gi  = proj[(0 * 8 + j) * 33 + b];
            float gf  = proj[(1 * 8 + j) * 33 + b];
            float gie = proj[(2 * 8 + j) * 33 + b];
            float gfe = proj[(3 * 8 + j) * 33 + b];
            float gz  = proj[(4 * 8 + j) * 33 + b];
            float go  = proj[(5 * 8 + j) * 33 + b];
            float z   = 2.f * gz - 1.f;
            float csn = gf * c_reg + gi * z;
            float cen = gfe * s_ce + gie * z;
            size_t ob = ((size_t)b * L_STEPS + t) * 3073;
            __builtin_nontemporal_store(go,  out1 + ob + c0 + j);
            __builtin_nontemporal_store(csn, out1 + ob + HDIM + c0 + j);
            __builtin_nontemporal_store(cen, out1 + ob + 2 * HDIM + c0 + j);
            s_o = go; s_cs = csn; s_ce = cen;
        }
        dt_cur = dt_nxt;
    }
}

extern "C" void kernel_launch(void* const* d_in, const int* in_sizes, int n_in,
                              void* d_out, int out_size, void* d_ws, size_t ws_size,
                              hipStream_t stream) {
    const float* x        = (const float*)d_in[0];
    const float* tdel     = (const float*)d_in[1];
    const float* o_state  = (const float*)d_in[2];
    const float* cs_state = (const float*)d_in[3];
    const float* ce_state = (const float*)d_in[4];
    const float* d_state  = (const float*)d_in[5];
    const float* weight   = (const float*)d_in[6];
    const float* bias     = (const float*)d_in[7];
    const float* d_weight = (const float*)d_in[8];
    const float* d_bias   = (const float*)d_in[9];
    const float* d_beta   = (const float*)d_in[10];

    float* out0 = (float*)d_out;
    float* out1 = out0 + (size_t)BATCH * L_STEPS * HDIM;

    unsigned short* flags = (unsigned short*)d_ws;
    __bf16* h0 = (__bf16*)((char*)d_ws + WS_FLAGS_BYTES);
    __bf16* h1 = (__bf16*)((char*)d_ws + WS_FLAGS_BYTES + (size_t)BATCH * HDIM * 2);

    (void)hipMemsetAsync(d_ws, 0, WS_FLAGS_BYTES, stream);  // re-arm flags every launch
    (void)hipFuncSetAttribute((const void*)ctlstm_kernel,
                              hipFuncAttributeMaxDynamicSharedMemorySize, LDS_BYTES);
    ctlstm_kernel<<<NWG, NTHREADS, LDS_BYTES, stream>>>(
        x, tdel, o_state, cs_state, ce_state, d_state,
        weight, bias, d_weight, d_bias, d_beta,
        out0, out1, flags, h0, h1);
}

// Round 9
// 3153.590 us; speedup vs baseline: 3.8397x; 1.4295x over previous
//
#include <hip/hip_runtime.h>
#include <hip/hip_bf16.h>

// ContTimeLSTM: L=512, B=32, DIN=512, H=1024.
// Persistent kernel: 128 WGs x 256 threads (4 waves, 1/SIMD, VGPR cap 512).
// WG g owns h-columns [8g, 8g+8) => 48 projection rows.
// R4 skeleton; h-stage uses NON-ATOMIC coalesced sc1 dwordx4 loads
// (1024 line-req/CU vs 8192 atomic 8-B req), software-pipelined with
// counted vmcnt waits. All addressing/swizzles identical to R4.

#define L_STEPS 512
#define BATCH   32
#define DIN     512
#define HDIM    1024
#define KDIM    1536
#define NWG     128
#define CPW     8
#define NTHREADS 256

// LDS layout (bytes)
#define LDS_XB0   0        // [32][512] bf16 swizzled  (32 KB)
#define LDS_XB1   32768
#define LDS_HB    65536    // [32][1024] bf16 swizzled (64 KB)
#define LDS_PROJ  131072   // 48*33 floats (6336 B)
#define LDS_DLS   137408   // 32 floats
#define LDS_HSTG  137536   // 256 bf16 (512 B)
#define LDS_BYTES 138048

#define WS_FLAGS_BYTES 1024              // 128 ushorts used

typedef __attribute__((ext_vector_type(8))) __bf16 bf16x8;
typedef __attribute__((ext_vector_type(4))) float  f32x4;
typedef __attribute__((ext_vector_type(4))) unsigned int u32x4;

__device__ __forceinline__ float fsigmoid(float u) { return 1.0f / (1.0f + __expf(-u)); }

__device__ __forceinline__ bf16x8 pack8(float4 fa, float4 fb) {
    bf16x8 v;
    v[0] = (__bf16)fa.x; v[1] = (__bf16)fa.y; v[2] = (__bf16)fa.z; v[3] = (__bf16)fa.w;
    v[4] = (__bf16)fb.x; v[5] = (__bf16)fb.y; v[6] = (__bf16)fb.z; v[7] = (__bf16)fb.w;
    return v;
}

__device__ __forceinline__ uint2 pack4(float4 f) {
    __bf16 b0 = (__bf16)f.x, b1 = (__bf16)f.y, b2 = (__bf16)f.z, b3 = (__bf16)f.w;
    unsigned short u0 = __builtin_bit_cast(unsigned short, b0);
    unsigned short u1 = __builtin_bit_cast(unsigned short, b1);
    unsigned short u2 = __builtin_bit_cast(unsigned short, b2);
    unsigned short u3 = __builtin_bit_cast(unsigned short, b3);
    uint2 v;
    v.x = (unsigned)u0 | ((unsigned)u1 << 16);
    v.y = (unsigned)u2 | ((unsigned)u3 << 16);
    return v;
}

extern "C" __global__ void __launch_bounds__(NTHREADS, 1)
ctlstm_kernel(const float* __restrict__ x,
              const float* __restrict__ tdel,
              const float* __restrict__ o_state,
              const float* __restrict__ cs_state,
              const float* __restrict__ ce_state,
              const float* __restrict__ d_state,
              const float* __restrict__ weight,
              const float* __restrict__ bias,
              const float* __restrict__ d_weight,
              const float* __restrict__ d_bias,
              const float* __restrict__ d_beta_p,
              float* __restrict__ out0,
              float* __restrict__ out1,
              unsigned short* __restrict__ flags,
              __bf16* __restrict__ h0,
              __bf16* __restrict__ h1)
{
    extern __shared__ char smem[];
    char*   hbp  = smem + LDS_HB;
    float*  proj = (float*)(smem + LDS_PROJ);
    float*  dls  = (float*)(smem + LDS_DLS);
    __bf16* hstg = (__bf16*)(smem + LDS_HSTG);

    const int tid = threadIdx.x;
    const int wg  = blockIdx.x;
    const int c0  = wg * CPW;

    const int wv = tid >> 6;       // 0..3: waves 0-2 gates, wave 3 = d
    const int l  = tid & 63;
    const int lr = l & 15;
    const int lk = l >> 4;

    // per-thread persistent state: (b, j), j in [0,8)
    const int b = tid >> 3, j = tid & 7;
    float s_o, s_cs, s_ce, dt_cur;
    {
        int gi = b * HDIM + c0 + j;
        s_o = o_state[gi]; s_cs = cs_state[gi]; s_ce = ce_state[gi];
        dt_cur = tdel[b];
    }
    if (tid < BATCH) dls[tid] = d_state[tid];

    // ---- startup: weights into registers (48 x bf16x8 per lane) ----
    bf16x8 Bx[16], Bh[32];
    float bias_r = 0.f;
    {
        const float* wsrc = nullptr;
        if (wv < 3) {
            int n = wv * 16 + lr, g = n >> 3, jj = n & 7;
            wsrc = weight + (size_t)(g * HDIM + c0 + jj) * KDIM;
            bias_r = bias[g * HDIM + c0 + jj];
        } else if (lr == 0) {
            wsrc = d_weight;
        }
        #pragma unroll
        for (int kc = 0; kc < 48; ++kc) {
            bf16x8 v = {};
            if (wsrc) {
                float4 fa = *(const float4*)(wsrc + kc * 32 + lk * 8);
                float4 fb = *(const float4*)(wsrc + kc * 32 + lk * 8 + 4);
                v = pack8(fa, fb);
            }
            if (kc < 16) Bx[kc] = v; else Bh[kc - 16] = v;
        }
    }
    const float dbias_s = d_bias[0];
    const float beta    = d_beta_p[0];

    // ---- startup: stage x panel 0 (R4 pattern) ----
    {
        const float* xp = x;
        #pragma unroll
        for (int r = 0; r < 16; ++r) {
            float4 f = *(const float4*)(xp + r * 1024 + tid * 4);
            int fo  = r * 1024 + tid * 4;
            int row = fo >> 9;
            int col = fo & 511;
            unsigned ba = (unsigned)(row * 1024 + col * 2);
            ba ^= ((unsigned)(row & 7)) << 4;
            *(uint2*)(smem + LDS_XB0 + ba) = pack4(f);
        }
    }
    __syncthreads();

    for (int t = 0; t < L_STEPS; ++t) {
        __bf16* hcur = (t & 1) ? h1 : h0;
        char* xcur = smem + ((t & 1) ? LDS_XB1 : LDS_XB0);
        char* xnxt = smem + ((t & 1) ? LDS_XB0 : LDS_XB1);

        // ---- phase 1: c, h; stage h slice in LDS ----
        float dv = dls[b];
        float c  = s_cs + (s_ce - s_cs) * __expf(-dv * dt_cur);
        float h_reg = s_o * (1.f - 2.f / (__expf(2.f * c) + 1.f));  // o*tanh(c)
        float c_reg = c;
        hstg[b * CPW + j] = (__bf16)h_reg;
        __syncthreads();   // S1

        // ---- wave 0: publish 512-B h slice (16-B sc1 stores), ack, flag ----
        if (tid < 64) {
            if (tid < 32) {
                u32x4 v = *(const u32x4*)((const char*)hstg + tid * 16);
                void* dst = (char*)hcur + (size_t)tid * 2048 + (unsigned)(wg * 16);
                asm volatile("global_store_dwordx4 %0, %1, off sc1" :: "v"(dst), "v"(v) : "memory");
            }
            asm volatile("s_waitcnt vmcnt(0)" ::: "memory");
            if (tid == 0)
                __hip_atomic_store(flags + wg, (unsigned short)(t + 1),
                                   __ATOMIC_RELAXED, __HIP_MEMORY_SCOPE_AGENT);
            asm volatile("" ::: "memory");
        }

        // ---- off-path: out0 store + tdel prefetch + next x panel loads ----
        __builtin_nontemporal_store(h_reg, out0 + ((size_t)b * L_STEPS + t) * HDIM + c0 + j);
        int tn = (t + 1 < L_STEPS) ? t + 1 : t;
        float dt_nxt = tdel[tn * BATCH + b];
        float4 xr[16];
        {
            const float* xp = x + (size_t)tn * BATCH * DIN;
            #pragma unroll
            for (int r = 0; r < 16; ++r)
                xr[r] = *(const float4*)(xp + r * 1024 + tid * 4);
        }

        // ---- x-part MFMA (overlaps barrier window; R4 swizzle) ----
        f32x4 acc0 = {0.f, 0.f, 0.f, 0.f};
        f32x4 acc1 = {0.f, 0.f, 0.f, 0.f};
        {
            const unsigned swz = ((unsigned)(lr & 7)) << 4;
            #pragma unroll
            for (int kc = 0; kc < 16; ++kc) {
                unsigned cb = (unsigned)(kc * 64 + lk * 16);
                bf16x8 a0 = *(const bf16x8*)(xcur + lr * 1024 + (cb ^ swz));
                bf16x8 a1 = *(const bf16x8*)(xcur + (16 + lr) * 1024 + (cb ^ swz));
                acc0 = __builtin_amdgcn_mfma_f32_16x16x32_bf16(a0, Bx[kc], acc0, 0, 0, 0);
                acc1 = __builtin_amdgcn_mfma_f32_16x16x32_bf16(a1, Bx[kc], acc1, 0, 0, 0);
            }
        }

        // ---- wave 0 polls packed flags ----
        if (tid < 64) {
            const unsigned tgt = (unsigned)(t + 1);
            const unsigned* fl = (const unsigned*)flags + l;   // 64 dwords = 128 flags
            for (;;) {
                unsigned v = __hip_atomic_load(fl, __ATOMIC_RELAXED, __HIP_MEMORY_SCOPE_AGENT);
                if (__all((int)((v & 0xFFFFu) >= tgt && (v >> 16) >= tgt))) break;
            }
        }
        __syncthreads();   // S2: all h published

        // ---- stage h: coalesced non-atomic sc1 dwordx4, pipelined 4-deep ----
        {
            const char* hcb = (const char*)hcur;
            u32x4 q0[4], q1[4], q2[4], q3[4];
            #define LD4(Q, BASE)                                                         \
                { _Pragma("unroll") for (int i = 0; i < 4; ++i) {                        \
                    const void* p = hcb + (BASE + i) * 4096 + tid * 16;                  \
                    asm volatile("global_load_dwordx4 %0, %1, off sc1"                   \
                                 : "=v"(Q[i]) : "v"(p) : "memory"); } }
            #define ST4(Q, BASE)                                                         \
                { _Pragma("unroll") for (int i = 0; i < 4; ++i) {                        \
                    unsigned g = (unsigned)(((BASE) + i) * 4096 + tid * 16);             \
                    unsigned row = g >> 11, colb = g & 2047;                             \
                    *(u32x4*)(hbp + row * 2048 + (colb ^ ((row & 7) << 4))) = Q[i]; } }
            LD4(q0, 0); LD4(q1, 4);
            asm volatile("s_waitcnt vmcnt(4)" ::: "memory");
            ST4(q0, 0); LD4(q2, 8);
            asm volatile("s_waitcnt vmcnt(4)" ::: "memory");
            ST4(q1, 4); LD4(q3, 12);
            asm volatile("s_waitcnt vmcnt(4)" ::: "memory");
            ST4(q2, 8);
            asm volatile("s_waitcnt vmcnt(0)" ::: "memory");
            ST4(q3, 12);
            #undef LD4
            #undef ST4
        }
        __syncthreads();   // S_stage: h tile ready

        // ---- convert + write next x panel (off critical path; R4 pattern) ----
        #pragma unroll
        for (int r = 0; r < 16; ++r) {
            int fo  = r * 1024 + tid * 4;
            int row = fo >> 9;
            int col = fo & 511;
            unsigned ba = (unsigned)(row * 1024 + col * 2);
            ba ^= ((unsigned)(row & 7)) << 4;
            *(uint2*)(xnxt + ba) = pack4(xr[r]);
        }

        // ---- h-part MFMA (R4 swizzle) ----
        {
            const unsigned swz = ((unsigned)(lr & 7)) << 4;
            #pragma unroll
            for (int kc = 0; kc < 32; ++kc) {
                unsigned cb = (unsigned)(kc * 64 + lk * 16);
                bf16x8 a0 = *(const bf16x8*)(hbp + lr * 2048 + (cb ^ swz));
                bf16x8 a1 = *(const bf16x8*)(hbp + (16 + lr) * 2048 + (cb ^ swz));
                acc0 = __builtin_amdgcn_mfma_f32_16x16x32_bf16(a0, Bh[kc], acc0, 0, 0, 0);
                acc1 = __builtin_amdgcn_mfma_f32_16x16x32_bf16(a1, Bh[kc], acc1, 0, 0, 0);
            }
        }

        if (wv < 3) {
            const int n = wv * 16 + lr;
            #pragma unroll
            for (int r = 0; r < 4; ++r) {
                proj[n * 33 + lk * 4 + r]      = fsigmoid(acc0[r] + bias_r);
                proj[n * 33 + 16 + lk * 4 + r] = fsigmoid(acc1[r] + bias_r);
            }
        } else if (lr == 0) {
            #pragma unroll
            for (int r = 0; r < 4; ++r) {
                int b0 = lk * 4 + r, b1 = 16 + lk * 4 + r;
                float bu0 = beta * (acc0[r] + dbias_s);
                float bu1 = beta * (acc1[r] + dbias_s);
                float sp0 = fmaxf(bu0, 0.f) + __logf(1.f + __expf(-fabsf(bu0)));
                float sp1 = fmaxf(bu1, 0.f) + __logf(1.f + __expf(-fabsf(bu1)));
                float dn0 = sp0 / beta, dn1 = sp1 / beta;
                dls[b0] = dn0; dls[b1] = dn1;
                if (wg == 0) {
                    __builtin_nontemporal_store(dn0, out1 + ((size_t)b0 * L_STEPS + t) * 3073 + 3072);
                    __builtin_nontemporal_store(dn1, out1 + ((size_t)b1 * L_STEPS + t) * 3073 + 3072);
                }
            }
        }
        __syncthreads();   // S3: proj + dls ready

        // ---- epilogue: gate algebra, state update, outputs ----
        {
            float gi  = proj[(0 * 8 + j) * 33 + b];
            float gf  = proj[(1 * 8 + j) * 33 + b];
            float gie = proj[(2 * 8 + j) * 33 + b];
            float gfe = proj[(3 * 8 + j) * 33 + b];
            float gz  = proj[(4 * 8 + j) * 33 + b];
            float go  = proj[(5 * 8 + j) * 33 + b];
            float z   = 2.f * gz - 1.f;
            float csn = gf * c_reg + gi * z;
            float cen = gfe * s_ce + gie * z;
            size_t ob = ((size_t)b * L_STEPS + t) * 3073;
            __builtin_nontemporal_store(go,  out1 + ob + c0 + j);
            __builtin_nontemporal_store(csn, out1 + ob + HDIM + c0 + j);
            __builtin_nontemporal_store(cen, out1 + ob + 2 * HDIM + c0 + j);
            s_o = go; s_cs = csn; s_ce = cen;
        }
        dt_cur = dt_nxt;
    }
}

extern "C" void kernel_launch(void* const* d_in, const int* in_sizes, int n_in,
                              void* d_out, int out_size, void* d_ws, size_t ws_size,
                              hipStream_t stream) {
    const float* x        = (const float*)d_in[0];
    const float* tdel     = (const float*)d_in[1];
    const float* o_state  = (const float*)d_in[2];
    const float* cs_state = (const float*)d_in[3];
    const float* ce_state = (const float*)d_in[4];
    const float* d_state  = (const float*)d_in[5];
    const float* weight   = (const float*)d_in[6];
    const float* bias     = (const float*)d_in[7];
    const float* d_weight = (const float*)d_in[8];
    const float* d_bias   = (const float*)d_in[9];
    const float* d_beta   = (const float*)d_in[10];

    float* out0 = (float*)d_out;
    float* out1 = out0 + (size_t)BATCH * L_STEPS * HDIM;

    unsigned short* flags = (unsigned short*)d_ws;
    __bf16* h0 = (__bf16*)((char*)d_ws + WS_FLAGS_BYTES);
    __bf16* h1 = (__bf16*)((char*)d_ws + WS_FLAGS_BYTES + (size_t)BATCH * HDIM * 2);

    (void)hipMemsetAsync(d_ws, 0, WS_FLAGS_BYTES, stream);  // re-arm flags every launch
    (void)hipFuncSetAttribute((const void*)ctlstm_kernel,
                              hipFuncAttributeMaxDynamicSharedMemorySize, LDS_BYTES);
    ctlstm_kernel<<<NWG, NTHREADS, LDS_BYTES, stream>>>(
        x, tdel, o_state, cs_state, ce_state, d_state,
        weight, bias, d_weight, d_bias, d_beta,
        out0, out1, flags, h0, h1);
}